// Round 12
// baseline (930.359 us; speedup 1.0000x reference)
//
#include <hip/hip_runtime.h>
#include <hip/hip_bf16.h>
#include <stdint.h>

// ---------------------------------------------------------------------------
// AdaptiveAngleConv: 5 angles of (bilinear deform-sample -> 3x3 conv)
// Conv v9 = round-10 (m97) structure with:
//  - BK=32, 72 steps tap-inner; LDS 32KB dbuf -> 34KB static -> 4 blocks/CU
//  - conflict-free 128B-line layout (2 px per line, slot=(px&1)*4+(s^(line&3)))
//  - fully constant-folded step constants (4x18 unroll), ds_read via
//    per-thread base + immediate offsets (zero per-step VALU on reads)
// ---------------------------------------------------------------------------

#define S2F 1.41421356237309515f

__constant__ float c_ox[5][9] = {
  {0.f,0.f,0.f,0.f,0.f,0.f,0.f,0.f,0.f},
  {1.f-S2F, 1.f-S2F*0.5f, 1.f, -S2F*0.5f, 0.f, S2F*0.5f, -1.f, S2F*0.5f-1.f, S2F-1.f},
  {0.f,1.f,2.f,-1.f,0.f,1.f,-2.f,-1.f,0.f},
  {1.f, 1.f+S2F*0.5f, 1.f+S2F, -S2F*0.5f, 0.f, S2F*0.5f, -1.f-S2F, -1.f-S2F*0.5f, -1.f},
  {2.f,2.f,2.f,0.f,0.f,0.f,-2.f,-2.f,-2.f}
};
__constant__ float c_oy[5][9] = {
  {0.f,0.f,0.f,0.f,0.f,0.f,0.f,0.f,0.f},
  {1.f, S2F*0.5f, S2F-1.f, 1.f-S2F*0.5f, 0.f, S2F*0.5f-1.f, 1.f-S2F, -S2F*0.5f, -1.f},
  {2.f,1.f,0.f,1.f,0.f,-1.f,0.f,-1.f,-2.f},
  {1.f+S2F, S2F*0.5f, -1.f, 1.f+S2F*0.5f, 0.f, -1.f-S2F*0.5f, 1.f, -S2F*0.5f, 1.f+S2F},
  {2.f,0.f,-2.f,2.f,0.f,-2.f,2.f,0.f,-2.f}
};

typedef __bf16 bf16x8_t __attribute__((ext_vector_type(8)));
typedef float f32x4_t __attribute__((ext_vector_type(4)));

typedef const __attribute__((address_space(1))) void* as1cp;
typedef __attribute__((address_space(3))) void* as3p;

__device__ __forceinline__ void gload16(const void* g, void* l) {
  __builtin_amdgcn_global_load_lds((as1cp)g, (as3p)l, 16, 0, 0);
}

// x NCHW (2,256,64,64) -> xT NHWC (2,64,64,256) f32
__global__ void k_transpose(const float* __restrict__ x, float* __restrict__ xT) {
  const int v = blockIdx.x, u = blockIdx.y, b = blockIdx.z;
  const int ic = threadIdx.x;
  xT[(((b*64 + u)*64 + v)*256) + ic] =
      x[(((b*256 + ic)*64 + u)*64) + v];
}

// weight OIHW (256,256,3,3) f32 -> wb (9,256,256)=[t][oc][ic] bf16
__global__ void k_wconv(const float* __restrict__ w, __hip_bfloat16* __restrict__ wb) {
  const int tid = blockIdx.x*256 + threadIdx.x;   // < 9*256*256
  const int t = tid >> 16;
  const int rem = tid & 65535;
  const int oc = rem >> 8;
  const int ic = rem & 255;
  wb[tid] = __float2bfloat16(w[(oc*256 + ic)*9 + t]);
}

// bilinear deform-sample -> xo bf16 NHWC [(a)][b][192][192][256]
__global__ void k_sample(const float* __restrict__ xT,
                         __hip_bfloat16* __restrict__ xo, int a0)
{
  const int aidx = a0 + blockIdx.z;
  __hip_bfloat16* xoa = xo + (size_t)blockIdx.z * (2ull*192*192*256);

  const int tid = threadIdx.x;           // 256
  const int ic = (tid & 63) * 4;
  const int j = blockIdx.x*4 + (tid >> 6);
  const int i = blockIdx.y;

  const int a = i / 3, r = i - 3*a;
  const int bc = j / 3, s = j - 3*bc;
  const int n = r*3 + s;
  const float px = (float)(a + r) + c_ox[aidx][n];
  const float py = (float)(bc + s) + c_oy[aidx][n];
  const float fx = floorf(px), fy = floorf(py);
  const float pxc = fminf(fmaxf(px, 0.f), 65.f);
  const float pyc = fminf(fmaxf(py, 0.f), 65.f);
  const int qlx = (int)fminf(fmaxf(fx,      0.f), 65.f);
  const int qrx = (int)fminf(fmaxf(fx + 1.f, 0.f), 65.f);
  const int qly = (int)fminf(fmaxf(fy,      0.f), 65.f);
  const int qry = (int)fminf(fmaxf(fy + 1.f, 0.f), 65.f);
  const float wlx = 1.f + (float)qlx - pxc;
  const float wrx = 1.f - (float)qrx + pxc;
  const float wly = 1.f + (float)qly - pyc;
  const float wry = 1.f - (float)qry + pyc;
  const float glt = wlx*wly, grb = wrx*wry, glb = wlx*wry, grt = wrx*wly;

  const bool inxl = (qlx >= 1) && (qlx <= 64);
  const bool inxr = (qrx >= 1) && (qrx <= 64);
  const bool inyl = (qly >= 1) && (qly <= 64);
  const bool inyr = (qry >= 1) && (qry <= 64);

  const f32x4_t zero = (f32x4_t){0.f,0.f,0.f,0.f};
  #pragma unroll
  for (int b = 0; b < 2; ++b) {
    const float* xb = xT + (size_t)b * (64*64*256);
    f32x4_t vlt = (inxl && inyl) ? *(const f32x4_t*)&xb[((qlx-1)*64 + (qly-1))*256 + ic] : zero;
    f32x4_t vrb = (inxr && inyr) ? *(const f32x4_t*)&xb[((qrx-1)*64 + (qry-1))*256 + ic] : zero;
    f32x4_t vlb = (inxl && inyr) ? *(const f32x4_t*)&xb[((qlx-1)*64 + (qry-1))*256 + ic] : zero;
    f32x4_t vrt = (inxr && inyl) ? *(const f32x4_t*)&xb[((qrx-1)*64 + (qly-1))*256 + ic] : zero;
    ushort4 pk;
    float v0 = glt*vlt[0] + grb*vrb[0] + glb*vlb[0] + grt*vrt[0];
    float v1 = glt*vlt[1] + grb*vrb[1] + glb*vlb[1] + grt*vrt[1];
    float v2 = glt*vlt[2] + grb*vrb[2] + glb*vlb[2] + grt*vrt[2];
    float v3 = glt*vlt[3] + grb*vrb[3] + glb*vlb[3] + grt*vrt[3];
    pk.x = __hip_bfloat16_raw(__float2bfloat16(v0)).x;
    pk.y = __hip_bfloat16_raw(__float2bfloat16(v1)).x;
    pk.z = __hip_bfloat16_raw(__float2bfloat16(v2)).x;
    pk.w = __hip_bfloat16_raw(__float2bfloat16(v3)).x;
    *(ushort4*)&xoa[(((size_t)b*192 + i)*192 + j)*256 + ic] = pk;
  }
}

// ---------------------------------------------------------------------------
// conv v9: implicit GEMM. grid (6, 95, nZ): x = octile(2) x coltile(3),
// y = row-pair, z = ab. Block 128px x 128oc, 4 waves (2Mx2N), wave 64x64
// via 4x4 frags of mfma_f32_16x16x32_bf16. BK=32, 72 steps tap-inner.
// LDS: A dbuf @0/8192 (8KB each, 64 lines x 128B, 2 px/line),
//      B dbuf @16384/24576; epilogue f32[64][132] overlays (33792 B).
// ---------------------------------------------------------------------------
__global__ __launch_bounds__(256, 4) void k_conv9(
    const __hip_bfloat16* __restrict__ xo,   // [z][192][192][256] bf16
    const __hip_bfloat16* __restrict__ wb,   // [9][256][256] bf16 (t,oc,ic)
    float* __restrict__ out)                 // + z*9241600 : [256][190][190]
{
  __shared__ __align__(16) char smem[33792];
  const int tid = threadIdx.x;
  const int nt = blockIdx.x & 1;
  const int ct = blockIdx.x >> 1;
  const int i0 = blockIdx.y * 2;
  const int z  = blockIdx.z;
  const int oc0 = nt * 128;
  const int j0 = ct * 64;

  const int w = tid >> 6, l = tid & 63;
  const int l15 = l & 15, lk = l >> 4;
  const int wm = w >> 1, wn = w & 1;

  const char* xob = (const char*)xo + (size_t)z * 18874368u;
  const char* wbc = (const char*)wb;

  // --- staging constants: thread stages chunks c=tid and c=256+tid ---
  // chunk c: line=c>>3, sp=c&7 -> px=((c>>3)<<1)|((c>>2)&1), s=(c&3)^((c>>3)&3)
  const int px0  = ((tid >> 3) << 1) | ((tid >> 2) & 1);   // 0..63 (col)
  const int s0   = (tid & 3) ^ ((tid >> 3) & 3);
  const int colv = j0 + px0;
  const unsigned aRow0 = (unsigned)(i0 * 98304 + s0 * 16);         // di=0 part
  const unsigned bB0   = (unsigned)((oc0 + px0) * 512 + s0 * 16);  // oc chunk0
  char* const aD0 = smem + w*1024;            // + cur*8192 (chunks 0..255)
  char* const aD1 = smem + 4096 + w*1024;     // (chunks 256..511, px+64)
  char* const bD0 = smem + 16384 + w*1024;
  char* const bD1 = smem + 16384 + 4096 + w*1024;

  // --- frag read base: px = wm*64+mf*16+l15, line=px>>1,
  //     sp=(px&1)*4 + (lk^(line&3)); (line&3)=((l15>>1)&3) for all mf/wm ---
  const int spq = (l15 & 1)*4 + (lk ^ ((l15 >> 1) & 3));
  const char* aRd = smem + (l15 >> 1)*128 + spq*16 + wm*4096;
  const char* bRd = aRd + 16384 + (wn - wm)*4096;

  f32x4_t acc[4][4];
  #pragma unroll
  for (int mf = 0; mf < 4; ++mf)
    #pragma unroll
    for (int nf = 0; nf < 4; ++nf)
      acc[mf][nf] = (f32x4_t){0.f, 0.f, 0.f, 0.f};

  auto stageT = [&](int tap, int icgOff, int cur) {  // tap,cur compile-time
    const int ki = (tap >= 6) ? 2 : ((tap >= 3) ? 1 : 0);
    const int kj = tap - ki*3;
    int j = colv + kj; if (j > 191) j = 191;
    const unsigned a0 = aRow0 + (unsigned)(ki*98304 + icgOff) + ((unsigned)j << 9);
    gload16(xob + a0,          aD0 + cur*8192);
    gload16(xob + a0 + 98304u, aD1 + cur*8192);
    const unsigned bc = (unsigned)(tap*131072 + icgOff);
    gload16(wbc + bB0 + bc,           bD0 + cur*8192);
    gload16(wbc + bB0 + 32768u + bc,  bD1 + cur*8192);
  };

  auto computeT = [&](int cur) {                     // cur compile-time
    bf16x8_t af[4], bf[4];
    #pragma unroll
    for (int mf = 0; mf < 4; ++mf)
      af[mf] = *(const bf16x8_t*)(aRd + cur*8192 + mf*1024);
    #pragma unroll
    for (int nf = 0; nf < 4; ++nf)
      bf[nf] = *(const bf16x8_t*)(bRd + cur*8192 + nf*1024);
    #pragma unroll
    for (int mf = 0; mf < 4; ++mf)
      #pragma unroll
      for (int nf = 0; nf < 4; ++nf)
        acc[mf][nf] = __builtin_amdgcn_mfma_f32_16x16x32_bf16(
            af[mf], bf[nf], acc[mf][nf], 0, 0, 0);
  };

  stageT(0, 0, 0);
  __syncthreads();

  for (int p = 0; p < 4; ++p) {          // icg pair p: icg = 2p, 2p+1
    const int off0 = p * 128;            // icg byte offset (icg*64)
    #pragma unroll
    for (int t = 0; t < 9; ++t) {        // kk = p*18 + t, cur = t&1
      if (t < 8) stageT(t + 1, off0, (t + 1) & 1);
      else       stageT(0, off0 + 64, 1);
      computeT(t & 1);
      __syncthreads();
    }
    #pragma unroll
    for (int t = 0; t < 9; ++t) {        // kk = p*18+9+t, cur = (t+1)&1
      if (t < 8)       stageT(t + 1, off0 + 64, t & 1);
      else if (p < 3)  stageT(0, off0 + 128, 0);
      computeT((t + 1) & 1);
      __syncthreads();
    }
  }

  // --- epilogue: 2 oc-half passes via eps f32[64][132] (33792 B) ---
  float* eps = (float*)smem;
  float* outb = out + (size_t)z * 9241600u;
  const int ocr = tid >> 2, q = tid & 3;
  const int iS = i0 + (q >> 1);                    // <= 189 always
  const int jb = j0 + (q & 1)*32;
  const int kmax = (ct == 2 && (q & 1)) ? 30 : 32;

  #pragma unroll
  for (int h = 0; h < 2; ++h) {
    __syncthreads();
    if (wn == h) {
      #pragma unroll
      for (int mf = 0; mf < 4; ++mf)
        #pragma unroll
        for (int nf = 0; nf < 4; ++nf)
          #pragma unroll
          for (int r = 0; r < 4; ++r)
            eps[(nf*16 + l15)*132 + wm*64 + mf*16 + lk*4 + r] = acc[mf][nf][r];
    }
    __syncthreads();
    {
      float* dst = outb + (size_t)(oc0 + h*64 + ocr)*36100u + iS*190 + jb;
      const float* src = eps + ocr*132 + q*32;
      for (int k = 0; k < kmax; k += 2)
        *(float2*)(dst + k) = make_float2(src[k], src[k + 1]);
    }
  }
}

extern "C" void kernel_launch(void* const* d_in, const int* in_sizes, int n_in,
                              void* d_out, int out_size, void* d_ws, size_t ws_size,
                              hipStream_t stream)
{
  const float* x = (const float*)d_in[0];
  const float* w = (const float*)d_in[1];
  float* out = (float*)d_out;

  char* ws = (char*)d_ws;
  float*          xT = (float*)ws;                         // 8,388,608 B
  __hip_bfloat16* wb = (__hip_bfloat16*)(ws + 8388608);    // 1,179,648 B
  __hip_bfloat16* xo = (__hip_bfloat16*)(ws + 9568256);    // 5 or 1 x 37,748,736 B

  const bool merged = (ws_size >= 198311936ull);

  k_transpose<<<dim3(64, 64, 2), 256, 0, stream>>>(x, xT);
  k_wconv<<<2304, 256, 0, stream>>>(w, wb);

  if (merged) {
    k_sample<<<dim3(48, 192, 5), 256, 0, stream>>>(xT, xo, 0);
    k_conv9<<<dim3(6, 95, 10), 256, 0, stream>>>(xo, wb, out);
  } else {
    for (int aidx = 0; aidx < 5; ++aidx) {
      k_sample<<<dim3(48, 192, 1), 256, 0, stream>>>(xT, xo, aidx);
      k_conv9<<<dim3(6, 95, 2), 256, 0, stream>>>(xo, wb, out + (size_t)aidx * 18483200u);
    }
  }
}

// Round 13
// 540.780 us; speedup vs baseline: 1.7204x; 1.7204x over previous
//
#include <hip/hip_runtime.h>
#include <hip/hip_bf16.h>
#include <stdint.h>

// ---------------------------------------------------------------------------
// AdaptiveAngleConv: 5 angles of (bilinear deform-sample -> 3x3 conv)
// x: (2,256,64,64) f32, weight: (256,256,3,3) f32
// out: 5 x (2,256,190,190) f32 concatenated
// Conv = round-10 kernel (m97 structure, 128x128 tile, BK=64, tap-inner,
// plain dbuf loop, 66KB LDS -> 2 blocks/CU, 886 TF) with ONE change:
// 1-D grid + pair-preserving XCD swizzle -- the two nt (oc-half) blocks of
// each (ct,y,z) pair share f mod 8 => same XCD => the A-window is fetched
// from HBM once and re-read from that XCD's L2 by the partner block.
// ---------------------------------------------------------------------------

#define S2F 1.41421356237309515f

__constant__ float c_ox[5][9] = {
  {0.f,0.f,0.f,0.f,0.f,0.f,0.f,0.f,0.f},
  {1.f-S2F, 1.f-S2F*0.5f, 1.f, -S2F*0.5f, 0.f, S2F*0.5f, -1.f, S2F*0.5f-1.f, S2F-1.f},
  {0.f,1.f,2.f,-1.f,0.f,1.f,-2.f,-1.f,0.f},
  {1.f, 1.f+S2F*0.5f, 1.f+S2F, -S2F*0.5f, 0.f, S2F*0.5f, -1.f-S2F, -1.f-S2F*0.5f, -1.f},
  {2.f,2.f,2.f,0.f,0.f,0.f,-2.f,-2.f,-2.f}
};
__constant__ float c_oy[5][9] = {
  {0.f,0.f,0.f,0.f,0.f,0.f,0.f,0.f,0.f},
  {1.f, S2F*0.5f, S2F-1.f, 1.f-S2F*0.5f, 0.f, S2F*0.5f-1.f, 1.f-S2F, -S2F*0.5f, -1.f},
  {2.f,1.f,0.f,1.f,0.f,-1.f,0.f,-1.f,-2.f},
  {1.f+S2F, S2F*0.5f, -1.f, 1.f+S2F*0.5f, 0.f, -1.f-S2F*0.5f, 1.f, -S2F*0.5f, 1.f+S2F},
  {2.f,0.f,-2.f,2.f,0.f,-2.f,2.f,0.f,-2.f}
};

typedef __bf16 bf16x8_t __attribute__((ext_vector_type(8)));
typedef float f32x4_t __attribute__((ext_vector_type(4)));

typedef const __attribute__((address_space(1))) void* as1cp;
typedef __attribute__((address_space(3))) void* as3p;

__device__ __forceinline__ void gload16(const void* g, void* l) {
  __builtin_amdgcn_global_load_lds((as1cp)g, (as3p)l, 16, 0, 0);
}

// x NCHW (2,256,64,64) -> xT NHWC (2,64,64,256) f32
__global__ void k_transpose(const float* __restrict__ x, float* __restrict__ xT) {
  const int v = blockIdx.x, u = blockIdx.y, b = blockIdx.z;
  const int ic = threadIdx.x;
  xT[(((b*64 + u)*64 + v)*256) + ic] =
      x[(((b*256 + ic)*64 + u)*64) + v];
}

// weight OIHW (256,256,3,3) f32 -> wb (9,256,256)=[t][oc][ic] bf16
__global__ void k_wconv(const float* __restrict__ w, __hip_bfloat16* __restrict__ wb) {
  const int tid = blockIdx.x*256 + threadIdx.x;   // < 9*256*256
  const int t = tid >> 16;
  const int rem = tid & 65535;
  const int oc = rem >> 8;
  const int ic = rem & 255;
  wb[tid] = __float2bfloat16(w[(oc*256 + ic)*9 + t]);
}

// bilinear deform-sample -> xo bf16 NHWC [(a)][b][192][192][256]
// grid (48, 192, nA): blockIdx.z selects angle (a0 + z); 4 ic per thread.
__global__ void k_sample(const float* __restrict__ xT,
                         __hip_bfloat16* __restrict__ xo, int a0)
{
  const int aidx = a0 + blockIdx.z;
  __hip_bfloat16* xoa = xo + (size_t)blockIdx.z * (2ull*192*192*256);

  const int tid = threadIdx.x;           // 256
  const int ic = (tid & 63) * 4;
  const int j = blockIdx.x*4 + (tid >> 6);
  const int i = blockIdx.y;

  const int a = i / 3, r = i - 3*a;
  const int bc = j / 3, s = j - 3*bc;
  const int n = r*3 + s;
  const float px = (float)(a + r) + c_ox[aidx][n];
  const float py = (float)(bc + s) + c_oy[aidx][n];
  const float fx = floorf(px), fy = floorf(py);
  const float pxc = fminf(fmaxf(px, 0.f), 65.f);
  const float pyc = fminf(fmaxf(py, 0.f), 65.f);
  const int qlx = (int)fminf(fmaxf(fx,      0.f), 65.f);
  const int qrx = (int)fminf(fmaxf(fx + 1.f, 0.f), 65.f);
  const int qly = (int)fminf(fmaxf(fy,      0.f), 65.f);
  const int qry = (int)fminf(fmaxf(fy + 1.f, 0.f), 65.f);
  const float wlx = 1.f + (float)qlx - pxc;
  const float wrx = 1.f - (float)qrx + pxc;
  const float wly = 1.f + (float)qly - pyc;
  const float wry = 1.f - (float)qry + pyc;
  const float glt = wlx*wly, grb = wrx*wry, glb = wlx*wry, grt = wrx*wly;

  const bool inxl = (qlx >= 1) && (qlx <= 64);
  const bool inxr = (qrx >= 1) && (qrx <= 64);
  const bool inyl = (qly >= 1) && (qly <= 64);
  const bool inyr = (qry >= 1) && (qry <= 64);

  const f32x4_t zero = (f32x4_t){0.f,0.f,0.f,0.f};
  #pragma unroll
  for (int b = 0; b < 2; ++b) {
    const float* xb = xT + (size_t)b * (64*64*256);
    f32x4_t vlt = (inxl && inyl) ? *(const f32x4_t*)&xb[((qlx-1)*64 + (qly-1))*256 + ic] : zero;
    f32x4_t vrb = (inxr && inyr) ? *(const f32x4_t*)&xb[((qrx-1)*64 + (qry-1))*256 + ic] : zero;
    f32x4_t vlb = (inxl && inyr) ? *(const f32x4_t*)&xb[((qlx-1)*64 + (qry-1))*256 + ic] : zero;
    f32x4_t vrt = (inxr && inyl) ? *(const f32x4_t*)&xb[((qrx-1)*64 + (qly-1))*256 + ic] : zero;
    ushort4 pk;
    float v0 = glt*vlt[0] + grb*vrb[0] + glb*vlb[0] + grt*vrt[0];
    float v1 = glt*vlt[1] + grb*vrb[1] + glb*vlb[1] + grt*vrt[1];
    float v2 = glt*vlt[2] + grb*vrb[2] + glb*vlb[2] + grt*vrt[2];
    float v3 = glt*vlt[3] + grb*vrb[3] + glb*vlb[3] + grt*vrt[3];
    pk.x = __hip_bfloat16_raw(__float2bfloat16(v0)).x;
    pk.y = __hip_bfloat16_raw(__float2bfloat16(v1)).x;
    pk.z = __hip_bfloat16_raw(__float2bfloat16(v2)).x;
    pk.w = __hip_bfloat16_raw(__float2bfloat16(v3)).x;
    *(ushort4*)&xoa[(((size_t)b*192 + i)*192 + j)*256 + ic] = pk;
  }
}

// implicit-GEMM conv: M=128 px (2 rows x 64 cols), N=128 oc, K=9 taps x 256 ic
// 1-D grid nblk = nZ*570. Pair-preserving XCD swizzle: for f in the 16-aligned
// body, blocks f = g*16+b and g*16+b+8 (b<8) form the nt=0/1 pair of one
// (ct,y,z) tile pair -> same f%8 -> same XCD -> shared A-window in L2.
__global__ __launch_bounds__(256, 2) void k_conv(
    const __hip_bfloat16* __restrict__ xo,   // [z][192][192][256] bf16
    const __hip_bfloat16* __restrict__ wb,   // [9][256][256] bf16 (t,oc,ic)
    float* __restrict__ out)                 // + z*9241600 : [256][190][190]
{
  __shared__ __align__(16) char smem[66048];
  const int tid = threadIdx.x;

  // --- pair-preserving swizzle decode (bijective; tail of <16 linear) ---
  const int f = blockIdx.x;
  const int T = gridDim.x & ~15;
  int pairI, nt;
  if (f < T) { pairI = (f >> 4)*8 + (f & 7); nt = (f >> 3) & 1; }
  else       { pairI = (T >> 1) + ((f - T) >> 1); nt = f & 1; }
  const int ct = pairI % 3;
  const int yz = pairI / 3;
  const int i0 = (yz % 95) * 2;
  const int z  = yz / 95;
  const int oc0 = nt * 128;
  const int j0 = ct * 64;

  const int q8   = tid >> 3;           // 0..31
  const int slot = tid & 7;
  const int wv   = tid >> 6;           // wave 0..3
  const int sw   = slot ^ (q8 & 7);    // XOR-swizzled 16B slot (pre-swizzle source)

  const char* xob = (const char*)xo + (size_t)z * 18874368u;
  const char* wbc = (const char*)wb;

  int arow[4], acol[4], brow[4];
  #pragma unroll
  for (int p = 0; p < 4; ++p) {
    const int m = p*32 + q8;
    arow[p] = i0 + (m >> 6);
    acol[p] = j0 + (m & 63);
    brow[p] = oc0 + m;
  }

  f32x4_t acc[4][4];
  #pragma unroll
  for (int fm = 0; fm < 4; ++fm)
    #pragma unroll
    for (int fn = 0; fn < 4; ++fn)
      acc[fm][fn] = (f32x4_t){0.f, 0.f, 0.f, 0.f};

  const int lane = tid & 63;
  const int lrow = lane & 15;
  const int lk   = lane >> 4;
  const int wm   = wv >> 1;
  const int wn   = wv & 1;

  auto stage = [&](int kk, int cur) {
    // TAP-INNER K order: tap = kk % 9, icg = kk / 9
    const int icg = kk / 9;
    const int t   = kk - icg*9;
    const int ki = t / 3, kj = t - 3*ki;
    char* sa = smem + cur*16384 + wv*1024;
    char* sb = smem + 32768 + cur*16384 + wv*1024;
    #pragma unroll
    for (int p = 0; p < 4; ++p) {
      int col = acol[p] + kj; col = (col > 191) ? 191 : col;   // garbage cols clamped (never stored)
      const char* ga = xob + (((arow[p] + ki)*192 + col)*256 + icg*64)*2 + sw*16;
      gload16(ga, sa + p*4096);
      const char* gb = wbc + ((t*256 + brow[p])*256 + icg*64)*2 + sw*16;
      gload16(gb, sb + p*4096);
    }
  };

  auto compute = [&](int cur) {
    const char* sa = smem + cur*16384;
    const char* sb = smem + 32768 + cur*16384;
    bf16x8_t af[4][2], bfr[4][2];
    #pragma unroll
    for (int fi = 0; fi < 4; ++fi) {
      const int m = wm*64 + fi*16 + lrow;
      const int n = wn*64 + fi*16 + lrow;
      #pragma unroll
      for (int ks = 0; ks < 2; ++ks) {
        af[fi][ks]  = *(const bf16x8_t*)(sa + m*128 + (((ks*4 + lk) ^ (m & 7)) * 16));
        bfr[fi][ks] = *(const bf16x8_t*)(sb + n*128 + (((ks*4 + lk) ^ (n & 7)) * 16));
      }
    }
    #pragma unroll
    for (int fm = 0; fm < 4; ++fm)
      #pragma unroll
      for (int fn = 0; fn < 4; ++fn)
        #pragma unroll
        for (int ks = 0; ks < 2; ++ks)
          acc[fm][fn] = __builtin_amdgcn_mfma_f32_16x16x32_bf16(
              af[fm][ks], bfr[fn][ks], acc[fm][fn], 0, 0, 0);
  };

  stage(0, 0);
  __syncthreads();
  for (int kk = 0; kk < 36; ++kk) {
    const int cur = kk & 1;
    if (kk < 35) stage(kk + 1, cur ^ 1);
    compute(cur);
    __syncthreads();
  }

  // epilogue: LDS transpose to [oc'][m'] (pad 129) for coalesced NCHW stores
  float* eps = (float*)smem;
  #pragma unroll
  for (int fm = 0; fm < 4; ++fm)
    #pragma unroll
    for (int fn = 0; fn < 4; ++fn)
      #pragma unroll
      for (int r = 0; r < 4; ++r)
        eps[(wn*64 + fn*16 + lrow)*129 + (wm*64 + fm*16 + lk*4 + r)] = acc[fm][fn][r];
  __syncthreads();

  float* outb = out + (size_t)z * 9241600u;
  #pragma unroll
  for (int pass = 0; pass < 16; ++pass) {
    const int ocw = pass*8 + (tid >> 5);
    const int m4  = (tid & 31) * 4;
    const int di  = m4 >> 6, jc = m4 & 63;
    const int i = i0 + di, j = j0 + jc;
    const float v0 = eps[ocw*129 + m4 + 0];
    const float v1 = eps[ocw*129 + m4 + 1];
    const float v2 = eps[ocw*129 + m4 + 2];
    const float v3 = eps[ocw*129 + m4 + 3];
    float* dst = outb + ((size_t)(oc0 + ocw)*190 + i)*190 + j;
    if (j + 3 < 190) {
      *(float2*)dst       = make_float2(v0, v1);   // 8B-aligned always
      *(float2*)(dst + 2) = make_float2(v2, v3);
    } else {
      if (j     < 190) dst[0] = v0;
      if (j + 1 < 190) dst[1] = v1;
      if (j + 2 < 190) dst[2] = v2;
      if (j + 3 < 190) dst[3] = v3;
    }
  }
}

extern "C" void kernel_launch(void* const* d_in, const int* in_sizes, int n_in,
                              void* d_out, int out_size, void* d_ws, size_t ws_size,
                              hipStream_t stream)
{
  const float* x = (const float*)d_in[0];
  const float* w = (const float*)d_in[1];
  float* out = (float*)d_out;

  char* ws = (char*)d_ws;
  float*          xT = (float*)ws;                         // 8,388,608 B
  __hip_bfloat16* wb = (__hip_bfloat16*)(ws + 8388608);    // 1,179,648 B
  __hip_bfloat16* xo = (__hip_bfloat16*)(ws + 9568256);    // 5 or 1 x 37,748,736 B

  const bool merged = (ws_size >= 198311936ull);

  k_transpose<<<dim3(64, 64, 2), 256, 0, stream>>>(x, xT);
  k_wconv<<<2304, 256, 0, stream>>>(w, wb);

  if (merged) {
    k_sample<<<dim3(48, 192, 5), 256, 0, stream>>>(xT, xo, 0);
    k_conv<<<5700, 256, 0, stream>>>(xo, wb, out);
  } else {
    for (int aidx = 0; aidx < 5; ++aidx) {
      k_sample<<<dim3(48, 192, 1), 256, 0, stream>>>(xT, xo, aidx);
      k_conv<<<1140, 256, 0, stream>>>(xo, wb, out + (size_t)aidx * 18483200u);
    }
  }
}